// Round 1
// baseline (256.832 us; speedup 1.0000x reference)
//
#include <hip/hip_runtime.h>
#include <math.h>

// ws layout: double[0]=ssq_w, double[1]=ssq_dw, double[2]=sum_abs,
// then floats at byte offset 24: f[0]=final_strength, f[1]=forgetting_strength

__global__ void wc_init(double* wsd) {
    wsd[0] = 0.0; wsd[1] = 0.0; wsd[2] = 0.0;
}

__global__ __launch_bounds__(256) void wc_reduce_ssq(const float4* __restrict__ w,
                                                     const float4* __restrict__ dw,
                                                     double* wsd, int n4) {
    int tid = blockIdx.x * blockDim.x + threadIdx.x;
    int stride = gridDim.x * blockDim.x;
    float sw = 0.f, sdw = 0.f;
    for (int i = tid; i < n4; i += stride) {
        float4 a = w[i];
        float4 b = dw[i];
        sw  = fmaf(a.x, a.x, fmaf(a.y, a.y, fmaf(a.z, a.z, fmaf(a.w, a.w, sw))));
        sdw = fmaf(b.x, b.x, fmaf(b.y, b.y, fmaf(b.z, b.z, fmaf(b.w, b.w, sdw))));
    }
    // wave (64-lane) reduction
    for (int off = 32; off > 0; off >>= 1) {
        sw  += __shfl_down(sw, off);
        sdw += __shfl_down(sdw, off);
    }
    __shared__ float lsw[4], lsdw[4];   // 256 threads = 4 waves
    int wave = threadIdx.x >> 6;
    int lane = threadIdx.x & 63;
    if (lane == 0) { lsw[wave] = sw; lsdw[wave] = sdw; }
    __syncthreads();
    if (threadIdx.x == 0) {
        float tw = lsw[0] + lsw[1] + lsw[2] + lsw[3];
        float tdw = lsdw[0] + lsdw[1] + lsdw[2] + lsdw[3];
        atomicAdd(&wsd[0], (double)tw);
        atomicAdd(&wsd[1], (double)tdw);
    }
}

__global__ void wc_scalars(const double* __restrict__ wsd, float* __restrict__ wsf,
                           const float* __restrict__ fg_w1, const float* __restrict__ fg_b1,
                           const float* __restrict__ fg_w2, const float* __restrict__ fg_b2,
                           float* __restrict__ out_tail) {
    // consolidation strength
    float normw = sqrtf((float)wsd[0]);
    float fs = 1.0f / (1.0f + expf(-normw));
    fs = fminf(fmaxf(fs, 0.0f), 1.0f);
    float cm = sqrtf((float)wsd[1]);
    // forgetting gate: input [0.01, 0.0001] -> Linear(2,8) -> ReLU -> Linear(8,1) -> Sigmoid
    const float tf = 0.01f, fr = 0.0001f;
    float acc = fg_b2[0];
    for (int j = 0; j < 8; j++) {
        float h = tf * fg_w1[2 * j + 0] + fr * fg_w1[2 * j + 1] + fg_b1[j];
        acc = fmaf(fmaxf(h, 0.0f), fg_w2[j], acc);
    }
    float fg = 1.0f / (1.0f + expf(-acc));
    wsf[0] = fs;
    wsf[1] = fg;
    out_tail[0] = fs;     // final_strength
    out_tail[1] = cm;     // change_magnitude
    out_tail[2] = fg;     // forgetting_strength
    out_tail[4] = 0.5f;   // weight_stability
    out_tail[5] = 0.0f;   // memory_strength
}

__global__ __launch_bounds__(256) void wc_consolidate(const float4* __restrict__ w,
                                                      float4* __restrict__ outw,
                                                      const float* __restrict__ ur_w1,
                                                      const float* __restrict__ ur_b1,
                                                      const float* __restrict__ ur_w2,
                                                      const float* __restrict__ ur_b2,
                                                      const float* __restrict__ wsf,
                                                      double* wsd, int n4) {
    float fs = wsf[0];
    float fg = wsf[1];
    float a0[16], hb[16], w2[16];
#pragma unroll
    for (int k = 0; k < 16; k++) {
        a0[k] = ur_w1[3 * k + 0];
        hb[k] = fmaf(fs, ur_w1[3 * k + 1], fmaf(fg, ur_w1[3 * k + 2], ur_b1[k]));
        w2[k] = ur_w2[k];
    }
    float b2 = ur_b2[0];

    int tid = blockIdx.x * blockDim.x + threadIdx.x;
    int stride = gridDim.x * blockDim.x;
    float sabs = 0.f;
    for (int i = tid; i < n4; i += stride) {
        float4 v = w[i];
        float r[4] = {v.x, v.y, v.z, v.w};
        float o[4];
#pragma unroll
        for (int e = 0; e < 4; e++) {
            float x = r[e];
            float acc = b2;
#pragma unroll
            for (int k = 0; k < 16; k++) {
                float h = fmaf(x, a0[k], hb[k]);
                acc = fmaf(fmaxf(h, 0.0f), w2[k], acc);
            }
            // tanh(acc) = 1 - 2/(exp(2*acc)+1)  (inf-safe, branchless)
            float t = __expf(2.0f * acc);
            float th = fmaf(-2.0f, __builtin_amdgcn_rcpf(t + 1.0f), 1.0f);
            float nw = fmaf(0.001f, th, x);
            nw = fminf(fmaxf(nw, -10.0f), 10.0f);
            o[e] = nw;
            sabs += fabsf(nw);
        }
        outw[i] = make_float4(o[0], o[1], o[2], o[3]);
    }
    // wave + block reduce sum of |new_w|
    for (int off = 32; off > 0; off >>= 1) sabs += __shfl_down(sabs, off);
    __shared__ float ls[4];
    int wave = threadIdx.x >> 6;
    int lane = threadIdx.x & 63;
    if (lane == 0) ls[wave] = sabs;
    __syncthreads();
    if (threadIdx.x == 0) {
        float tb = ls[0] + ls[1] + ls[2] + ls[3];
        atomicAdd(&wsd[2], (double)tb);
    }
}

__global__ void wc_finalize(const double* __restrict__ wsd, float* __restrict__ out_tail, double n) {
    float mean_abs = (float)(wsd[2] / n);
    float dq = (mean_abs > 0.1f && mean_abs < 0.9f) ? 1.0f : mean_abs;
    out_tail[3] = (0.5f + dq) * 0.5f;  // consolidation_quality
}

extern "C" void kernel_launch(void* const* d_in, const int* in_sizes, int n_in,
                              void* d_out, int out_size, void* d_ws, size_t ws_size,
                              hipStream_t stream) {
    const float* cur_w = (const float*)d_in[0];
    const float* w_chg = (const float*)d_in[1];
    const float* ur_w1 = (const float*)d_in[2];
    const float* ur_b1 = (const float*)d_in[3];
    const float* ur_w2 = (const float*)d_in[4];
    const float* ur_b2 = (const float*)d_in[5];
    const float* fg_w1 = (const float*)d_in[6];
    const float* fg_b1 = (const float*)d_in[7];
    const float* fg_w2 = (const float*)d_in[8];
    const float* fg_b2 = (const float*)d_in[9];

    int n = in_sizes[0];          // 16777216, divisible by 4
    int n4 = n / 4;

    double* wsd = (double*)d_ws;
    float* wsf = (float*)((char*)d_ws + 3 * sizeof(double));

    float* out_w = (float*)d_out;
    float* out_tail = out_w + n;

    wc_init<<<1, 1, 0, stream>>>(wsd);

    const int threads = 256;
    const int blocks = 2048;   // grid-stride; 256 CUs comfortably oversubscribed
    wc_reduce_ssq<<<blocks, threads, 0, stream>>>((const float4*)cur_w, (const float4*)w_chg, wsd, n4);

    wc_scalars<<<1, 1, 0, stream>>>(wsd, wsf, fg_w1, fg_b1, fg_w2, fg_b2, out_tail);

    wc_consolidate<<<blocks, threads, 0, stream>>>((const float4*)cur_w, (float4*)out_w,
                                                   ur_w1, ur_b1, ur_w2, ur_b2, wsf, wsd, n4);

    wc_finalize<<<1, 1, 0, stream>>>(wsd, out_tail, (double)n);
}

// Round 3
// 237.145 us; speedup vs baseline: 1.0830x; 1.0830x over previous
//
#include <hip/hip_runtime.h>
#include <math.h>

// Use a true clang vector type: __builtin_nontemporal_load/store accept it
// (HIP_vector_type<float,4> is a struct and is rejected).
typedef float vfloat4 __attribute__((ext_vector_type(4)));

// ws layout: double[0]=ssq_w, double[1]=ssq_dw, double[2]=sum_abs,
// then floats at byte offset 24: f[0]=final_strength, f[1]=forgetting_strength

__global__ void wc_init(double* wsd) {
    wsd[0] = 0.0; wsd[1] = 0.0; wsd[2] = 0.0;
}

// Unroll factor: 8 independent 16B loads per array per thread, issued before
// any use -> ~16 loads in flight per wave (MLP fix for the 1.5 TB/s
// latency-bound R0 kernel: VALUBusy was 2.4%, hbm 9.7%).
#define RED_UNROLL 8

__global__ __launch_bounds__(256) void wc_reduce_ssq(const vfloat4* __restrict__ w,
                                                     const vfloat4* __restrict__ dw,
                                                     double* wsd, int n4) {
    int tid = blockIdx.x * blockDim.x + threadIdx.x;
    int stride = gridDim.x * blockDim.x;
    float sw0 = 0.f, sw1 = 0.f, sw2 = 0.f, sw3 = 0.f;
    float sd0 = 0.f, sd1 = 0.f, sd2 = 0.f, sd3 = 0.f;
    int i = tid;
    for (; i + (RED_UNROLL - 1) * stride < n4; i += RED_UNROLL * stride) {
        vfloat4 a[RED_UNROLL], b[RED_UNROLL];
#pragma unroll
        for (int u = 0; u < RED_UNROLL; u++) a[u] = w[i + u * stride];
#pragma unroll
        for (int u = 0; u < RED_UNROLL; u++) b[u] = __builtin_nontemporal_load(&dw[i + u * stride]);
#pragma unroll
        for (int u = 0; u < RED_UNROLL; u++) {
            sw0 = fmaf(a[u].x, a[u].x, sw0);
            sw1 = fmaf(a[u].y, a[u].y, sw1);
            sw2 = fmaf(a[u].z, a[u].z, sw2);
            sw3 = fmaf(a[u].w, a[u].w, sw3);
            sd0 = fmaf(b[u].x, b[u].x, sd0);
            sd1 = fmaf(b[u].y, b[u].y, sd1);
            sd2 = fmaf(b[u].z, b[u].z, sd2);
            sd3 = fmaf(b[u].w, b[u].w, sd3);
        }
    }
    for (; i < n4; i += stride) {
        vfloat4 a = w[i];
        vfloat4 b = dw[i];
        sw0 = fmaf(a.x, a.x, sw0); sw1 = fmaf(a.y, a.y, sw1);
        sw2 = fmaf(a.z, a.z, sw2); sw3 = fmaf(a.w, a.w, sw3);
        sd0 = fmaf(b.x, b.x, sd0); sd1 = fmaf(b.y, b.y, sd1);
        sd2 = fmaf(b.z, b.z, sd2); sd3 = fmaf(b.w, b.w, sd3);
    }
    float sw = (sw0 + sw1) + (sw2 + sw3);
    float sdw = (sd0 + sd1) + (sd2 + sd3);
    // wave (64-lane) reduction
    for (int off = 32; off > 0; off >>= 1) {
        sw  += __shfl_down(sw, off);
        sdw += __shfl_down(sdw, off);
    }
    __shared__ float lsw[4], lsdw[4];   // 256 threads = 4 waves
    int wave = threadIdx.x >> 6;
    int lane = threadIdx.x & 63;
    if (lane == 0) { lsw[wave] = sw; lsdw[wave] = sdw; }
    __syncthreads();
    if (threadIdx.x == 0) {
        float tw = lsw[0] + lsw[1] + lsw[2] + lsw[3];
        float tdw = lsdw[0] + lsdw[1] + lsdw[2] + lsdw[3];
        atomicAdd(&wsd[0], (double)tw);
        atomicAdd(&wsd[1], (double)tdw);
    }
}

__global__ void wc_scalars(const double* __restrict__ wsd, float* __restrict__ wsf,
                           const float* __restrict__ fg_w1, const float* __restrict__ fg_b1,
                           const float* __restrict__ fg_w2, const float* __restrict__ fg_b2,
                           float* __restrict__ out_tail) {
    float normw = sqrtf((float)wsd[0]);
    float fs = 1.0f / (1.0f + expf(-normw));
    fs = fminf(fmaxf(fs, 0.0f), 1.0f);
    float cm = sqrtf((float)wsd[1]);
    const float tf = 0.01f, fr = 0.0001f;
    float acc = fg_b2[0];
    for (int j = 0; j < 8; j++) {
        float h = tf * fg_w1[2 * j + 0] + fr * fg_w1[2 * j + 1] + fg_b1[j];
        acc = fmaf(fmaxf(h, 0.0f), fg_w2[j], acc);
    }
    float fg = 1.0f / (1.0f + expf(-acc));
    wsf[0] = fs;
    wsf[1] = fg;
    out_tail[0] = fs;     // final_strength
    out_tail[1] = cm;     // change_magnitude
    out_tail[2] = fg;     // forgetting_strength
    out_tail[4] = 0.5f;   // weight_stability
    out_tail[5] = 0.0f;   // memory_strength
}

#define CON_UNROLL 8

__global__ __launch_bounds__(256) void wc_consolidate(const vfloat4* __restrict__ w,
                                                      vfloat4* __restrict__ outw,
                                                      const float* __restrict__ ur_w1,
                                                      const float* __restrict__ ur_b1,
                                                      const float* __restrict__ ur_w2,
                                                      const float* __restrict__ ur_b2,
                                                      const float* __restrict__ wsf,
                                                      double* wsd, int n4) {
    float fs = wsf[0];
    float fg = wsf[1];
    // Wave-uniform loads from kernel-arg pointers -> SGPRs (s_load), so they
    // don't eat VGPR occupancy.
    float a0[16], hb[16], w2[16];
#pragma unroll
    for (int k = 0; k < 16; k++) {
        a0[k] = ur_w1[3 * k + 0];
        hb[k] = fmaf(fs, ur_w1[3 * k + 1], fmaf(fg, ur_w1[3 * k + 2], ur_b1[k]));
        w2[k] = ur_w2[k];
    }
    float b2 = ur_b2[0];

    int tid = blockIdx.x * blockDim.x + threadIdx.x;
    int stride = gridDim.x * blockDim.x;
    float sabs = 0.f;
    int i = tid;
    for (; i + (CON_UNROLL - 1) * stride < n4; i += CON_UNROLL * stride) {
        vfloat4 v[CON_UNROLL];
#pragma unroll
        for (int u = 0; u < CON_UNROLL; u++) v[u] = w[i + u * stride];
#pragma unroll
        for (int u = 0; u < CON_UNROLL; u++) {
            float r[4] = {v[u].x, v[u].y, v[u].z, v[u].w};
            vfloat4 o;
#pragma unroll
            for (int e = 0; e < 4; e++) {
                float x = r[e];
                float acc = b2;
#pragma unroll
                for (int k = 0; k < 16; k++) {
                    float h = fmaf(x, a0[k], hb[k]);
                    acc = fmaf(fmaxf(h, 0.0f), w2[k], acc);
                }
                float t = __expf(2.0f * acc);
                float th = fmaf(-2.0f, __builtin_amdgcn_rcpf(t + 1.0f), 1.0f);
                float nw = fmaf(0.001f, th, x);
                nw = fminf(fmaxf(nw, -10.0f), 10.0f);
                o[e] = nw;
                sabs += fabsf(nw);
            }
            __builtin_nontemporal_store(o, &outw[i + u * stride]);
        }
    }
    for (; i < n4; i += stride) {
        vfloat4 v = w[i];
        float r[4] = {v.x, v.y, v.z, v.w};
        vfloat4 o;
#pragma unroll
        for (int e = 0; e < 4; e++) {
            float x = r[e];
            float acc = b2;
#pragma unroll
            for (int k = 0; k < 16; k++) {
                float h = fmaf(x, a0[k], hb[k]);
                acc = fmaf(fmaxf(h, 0.0f), w2[k], acc);
            }
            float t = __expf(2.0f * acc);
            float th = fmaf(-2.0f, __builtin_amdgcn_rcpf(t + 1.0f), 1.0f);
            float nw = fmaf(0.001f, th, x);
            nw = fminf(fmaxf(nw, -10.0f), 10.0f);
            o[e] = nw;
            sabs += fabsf(nw);
        }
        outw[i] = o;
    }
    for (int off = 32; off > 0; off >>= 1) sabs += __shfl_down(sabs, off);
    __shared__ float ls[4];
    int wave = threadIdx.x >> 6;
    int lane = threadIdx.x & 63;
    if (lane == 0) ls[wave] = sabs;
    __syncthreads();
    if (threadIdx.x == 0) {
        float tb = ls[0] + ls[1] + ls[2] + ls[3];
        atomicAdd(&wsd[2], (double)tb);
    }
}

__global__ void wc_finalize(const double* __restrict__ wsd, float* __restrict__ out_tail, double n) {
    float mean_abs = (float)(wsd[2] / n);
    float dq = (mean_abs > 0.1f && mean_abs < 0.9f) ? 1.0f : mean_abs;
    out_tail[3] = (0.5f + dq) * 0.5f;  // consolidation_quality
}

extern "C" void kernel_launch(void* const* d_in, const int* in_sizes, int n_in,
                              void* d_out, int out_size, void* d_ws, size_t ws_size,
                              hipStream_t stream) {
    const float* cur_w = (const float*)d_in[0];
    const float* w_chg = (const float*)d_in[1];
    const float* ur_w1 = (const float*)d_in[2];
    const float* ur_b1 = (const float*)d_in[3];
    const float* ur_w2 = (const float*)d_in[4];
    const float* ur_b2 = (const float*)d_in[5];
    const float* fg_w1 = (const float*)d_in[6];
    const float* fg_b1 = (const float*)d_in[7];
    const float* fg_w2 = (const float*)d_in[8];
    const float* fg_b2 = (const float*)d_in[9];

    int n = in_sizes[0];          // 16777216 (4096x4096)
    int n4 = n / 4;

    double* wsd = (double*)d_ws;
    float* wsf = (float*)((char*)d_ws + 3 * sizeof(double));

    float* out_w = (float*)d_out;
    float* out_tail = out_w + n;

    wc_init<<<1, 1, 0, stream>>>(wsd);

    const int threads = 256;
    const int blocks = 2048;   // 2048*256*8(unroll)*4(float4) == 16.7M exactly: no tail
    wc_reduce_ssq<<<blocks, threads, 0, stream>>>((const vfloat4*)cur_w, (const vfloat4*)w_chg, wsd, n4);

    wc_scalars<<<1, 1, 0, stream>>>(wsd, wsf, fg_w1, fg_b1, fg_w2, fg_b2, out_tail);

    wc_consolidate<<<blocks, threads, 0, stream>>>((const vfloat4*)cur_w, (vfloat4*)out_w,
                                                   ur_w1, ur_b1, ur_w2, ur_b2, wsf, wsd, n4);

    wc_finalize<<<1, 1, 0, stream>>>(wsd, out_tail, (double)n);
}